// Round 3
// baseline (238.557 us; speedup 1.0000x reference)
//
#include <hip/hip_runtime.h>
#include <cstdint>
#include <cstddef>

typedef unsigned short u16;
typedef __attribute__((ext_vector_type(8))) short bf16x8;
typedef __attribute__((ext_vector_type(4))) float f32x4;

__device__ inline float bl(uint32_t u){ union{float f;uint32_t i;}c; c.i = u<<16; return c.f; }
__device__ inline float bh(uint32_t u){ union{float f;uint32_t i;}c; c.i = u & 0xFFFF0000u; return c.f; }
__device__ inline u16 f2bu(float f){
  union{float f;uint32_t u;} c; c.f=f;
  uint32_t u=c.u;
  return (u16)((u + 0x7FFFu + ((u>>16)&1u))>>16);  // RNE
}

#define GLOAD_LDS16(g, l) __builtin_amdgcn_global_load_lds( \
    (__attribute__((address_space(1))) void*)(g), \
    (__attribute__((address_space(3))) void*)(l), 16, 0, 0)

// ---------------- convert x: f32 -> bf16 ----------------
__global__ __launch_bounds__(256) void k_conv_x(const float* __restrict__ X,
                                                u16* __restrict__ Xb, int n4){
  int i = blockIdx.x*256 + threadIdx.x;
  int stride = gridDim.x*256;
  for (; i < n4; i += stride){
    float4 v = ((const float4*)X)[i];
    ushort4 o;
    o.x=f2bu(v.x); o.y=f2bu(v.y); o.z=f2bu(v.z); o.w=f2bu(v.w);
    ((ushort4*)Xb)[i] = o;
  }
}

// ---------------- transpose+convert W: [1024][3072] f32 -> [3072][1024] bf16 ----------------
__global__ __launch_bounds__(256) void k_conv_wt(const float* __restrict__ W,
                                                 u16* __restrict__ Wt){
  __shared__ float t[32][33];
  int n0 = blockIdx.x*32, k0 = blockIdx.y*32;
  int tx = threadIdx.x & 31, ty = threadIdx.x >> 5;
  #pragma unroll
  for (int i=0;i<32;i+=8)
    t[ty+i][tx] = W[(size_t)(k0+ty+i)*3072 + n0+tx];
  __syncthreads();
  #pragma unroll
  for (int i=0;i<32;i+=8)
    Wt[(size_t)(n0+ty+i)*1024 + k0+tx] = f2bu(t[tx][ty+i]);
}

// ---------------- GEMM: Qkv[M=16384][N=3072] = Xb[M][K=1024] * Wt[N][K]^T + bias ----------------
// m97 structure: 128x128 tile, BK=32, 4 waves, 4x4 frags of 16x16x32 bf16 MFMA,
// global_load_lds width=16 staging, 2 barriers per K-step.
template<typename OT>
__global__ __launch_bounds__(256) void k_gemm(const u16* __restrict__ Xb,
                                              const u16* __restrict__ Wt,
                                              const float* __restrict__ bias,
                                              OT* __restrict__ Q){
  __shared__ __align__(16) u16 As[128*32];
  __shared__ __align__(16) u16 Bs[128*32];
  const int K = 1024, N = 3072;
  int b = blockIdx.x;
  // XCD-aware swizzle (nwg=3072, 3072%8==0 -> bijective)
  int swz = (b & 7)*384 + (b >> 3);
  int bm = swz / 24, bn = swz % 24;
  int m0 = bm*128, n0 = bn*128;
  int tid = threadIdx.x, w = tid>>6, lane = tid&63, lr = lane&15, lk = lane>>4;
  int wr = w>>1, wc = w&1;

  f32x4 acc[4][4];
  #pragma unroll
  for (int i=0;i<4;i++)
    #pragma unroll
    for (int j=0;j<4;j++)
      acc[i][j] = (f32x4){0.f,0.f,0.f,0.f};

  // staging: 8 chunks of 1024B per matrix; wave w owns chunks 2w, 2w+1.
  int e0 = (2*w)*512 + lane*8;   // bf16 element index within tile (linear [row][32k])
  int e1 = e0 + 512;
  const u16* gA0 = Xb + (size_t)(m0 + (e0>>5))*K + (e0&31);
  const u16* gA1 = Xb + (size_t)(m0 + (e1>>5))*K + (e1&31);
  const u16* gB0 = Wt + (size_t)(n0 + (e0>>5))*K + (e0&31);
  const u16* gB1 = Wt + (size_t)(n0 + (e1>>5))*K + (e1&31);
  u16* lA0 = &As[(2*w)*512]; u16* lA1 = &As[(2*w)*512 + 512];
  u16* lB0 = &Bs[(2*w)*512]; u16* lB1 = &Bs[(2*w)*512 + 512];

  for (int kt = 0; kt < K; kt += 32){
    GLOAD_LDS16(gA0 + kt, lA0);
    GLOAD_LDS16(gA1 + kt, lA1);
    GLOAD_LDS16(gB0 + kt, lB0);
    GLOAD_LDS16(gB1 + kt, lB1);
    __syncthreads();   // drains vmcnt before reads

    bf16x8 af[4], bfr[4];
    #pragma unroll
    for (int mi=0;mi<4;mi++)
      af[mi] = *(const bf16x8*)&As[(wr*64 + mi*16 + lr)*32 + lk*8];
    #pragma unroll
    for (int ni=0;ni<4;ni++)
      bfr[ni] = *(const bf16x8*)&Bs[(wc*64 + ni*16 + lr)*32 + lk*8];
    #pragma unroll
    for (int mi=0;mi<4;mi++)
      #pragma unroll
      for (int ni=0;ni<4;ni++)
        acc[mi][ni] = __builtin_amdgcn_mfma_f32_16x16x32_bf16(af[mi], bfr[ni], acc[mi][ni], 0, 0, 0);
    __syncthreads();   // protect LDS before next stage
  }

  // epilogue: C/D layout col=lane&15, row=(lane>>4)*4+reg  [m89-verified]
  #pragma unroll
  for (int ni=0;ni<4;ni++){
    int col = n0 + wc*64 + ni*16 + lr;
    float bv = bias[col];
    #pragma unroll
    for (int mi=0;mi<4;mi++){
      int rowb = m0 + wr*64 + mi*16 + lk*4;
      #pragma unroll
      for (int r=0;r<4;r++){
        float v = acc[mi][ni][r] + bv;
        size_t idx = (size_t)(rowb + r)*N + col;
        if constexpr (sizeof(OT) == 2) Q[idx] = f2bu(v);
        else                           Q[idx] = v;
      }
    }
  }
}

// ---------------- per-token head-attention ----------------
template<typename T> __device__ inline void load16f(const T* p, float* f);
template<> __device__ inline void load16f<u16>(const u16* p, float* f){
  uint4 a = ((const uint4*)p)[0], b4 = ((const uint4*)p)[1];
  f[0]=bl(a.x);  f[1]=bh(a.x);  f[2]=bl(a.y);  f[3]=bh(a.y);
  f[4]=bl(a.z);  f[5]=bh(a.z);  f[6]=bl(a.w);  f[7]=bh(a.w);
  f[8]=bl(b4.x); f[9]=bh(b4.x); f[10]=bl(b4.y);f[11]=bh(b4.y);
  f[12]=bl(b4.z);f[13]=bh(b4.z);f[14]=bl(b4.w);f[15]=bh(b4.w);
}
template<> __device__ inline void load16f<float>(const float* p, float* f){
  #pragma unroll
  for (int i=0;i<4;i++){
    float4 v = ((const float4*)p)[i];
    f[i*4+0]=v.x; f[i*4+1]=v.y; f[i*4+2]=v.z; f[i*4+3]=v.w;
  }
}

// 1 wave per token; lane = h*4 + dq; dq owns d in [dq*16, dq*16+16).
template<typename T>
__global__ __launch_bounds__(256) void k_attn(const T* __restrict__ Qkv,
                                              float* __restrict__ out){
  __shared__ __align__(16) T sm[4][3072];
  int w = threadIdx.x>>6, lane = threadIdx.x&63;
  int token = blockIdx.x*4 + w;
  const uint4* src = (const uint4*)(Qkv + (size_t)token*3072);
  uint4* dst = (uint4*)&sm[w][0];
  const int nv = (int)(3072*sizeof(T)/16);
  for (int i = lane; i < nv; i += 64) dst[i] = src[i];
  __syncthreads();

  int h = lane>>2, dq = lane&3;
  const T* base = &sm[w][0];
  float qf[16];
  load16f(base + h*192 + dq*16, qf);

  const float scale = 0.07216878364870323f;  // 1/sqrt(192)
  float s[16];
  #pragma unroll
  for (int g=0; g<16; ++g){
    float kf[16];
    load16f(base + g*192 + 64 + dq*16, kf);
    float a = 0.f;
    #pragma unroll
    for (int j=0;j<16;j++) a += qf[j]*kf[j];
    a += __shfl_xor(a, 1);   // reduce over the 4 d-quarters
    a += __shfl_xor(a, 2);
    s[g] = a * scale;
  }
  float mx = s[0];
  #pragma unroll
  for (int g=1; g<16; ++g) mx = fmaxf(mx, s[g]);
  float sum = 0.f;
  #pragma unroll
  for (int g=0; g<16; ++g){ s[g] = __expf(s[g]-mx); sum += s[g]; }
  float inv = 1.f/sum;

  float o[16];
  #pragma unroll
  for (int j=0;j<16;j++) o[j] = 0.f;
  #pragma unroll
  for (int g=0; g<16; ++g){
    float wg = s[g]*inv;
    float vf[16];
    load16f(base + g*192 + 128 + dq*16, vf);
    #pragma unroll
    for (int j=0;j<16;j++) o[j] += wg*vf[j];
  }
  float* op = out + (size_t)token*1024 + h*64 + dq*16;
  #pragma unroll
  for (int i=0;i<4;i++)
    ((float4*)op)[i] = make_float4(o[i*4], o[i*4+1], o[i*4+2], o[i*4+3]);
}

// ---------------- fallback (ws too small): fully fused, f32 VALU, slow but correct ----------------
__global__ __launch_bounds__(256) void k_fallback(const float* __restrict__ X,
                                                  const float* __restrict__ W,
                                                  const float* __restrict__ bias,
                                                  float* __restrict__ out){
  int token = blockIdx.x;
  __shared__ float xs[1024];
  __shared__ float qkvs[3072];
  __shared__ float ss[16][16];
  __shared__ float ww[16][16];
  for (int i=threadIdx.x; i<1024; i+=256) xs[i] = X[(size_t)token*1024 + i];
  __syncthreads();
  for (int n=threadIdx.x; n<3072; n+=256){
    float acc = bias[n];
    for (int k=0;k<1024;k++) acc += xs[k]*W[(size_t)k*3072 + n];
    qkvs[n] = acc;
  }
  __syncthreads();
  {
    int t = threadIdx.x, h = t>>4, g = t&15;
    float a = 0.f;
    for (int d=0; d<64; d++) a += qkvs[h*192 + d]*qkvs[g*192 + 64 + d];
    ss[h][g] = a * 0.07216878364870323f;
  }
  __syncthreads();
  if (threadIdx.x < 16){
    int hh = threadIdx.x;
    float m = -1e30f;
    for (int g=0;g<16;g++) m = fmaxf(m, ss[hh][g]);
    float sum = 0.f;
    for (int g=0;g<16;g++){ float e = __expf(ss[hh][g]-m); ww[hh][g]=e; sum+=e; }
    float inv = 1.f/sum;
    for (int g=0;g<16;g++) ww[hh][g] *= inv;
  }
  __syncthreads();
  for (int i=threadIdx.x; i<1024; i+=256){
    int h = i>>6, d = i&63;
    float a = 0.f;
    for (int g=0;g<16;g++) a += ww[h][g]*qkvs[g*192 + 128 + d];
    out[(size_t)token*1024 + i] = a;
  }
}

extern "C" void kernel_launch(void* const* d_in, const int* in_sizes, int n_in,
                              void* d_out, int out_size, void* d_ws, size_t ws_size,
                              hipStream_t stream){
  const float* x    = (const float*)d_in[0];   // [4,4096,1024] f32
  const float* wk   = (const float*)d_in[1];   // [1024,16,192] f32
  const float* bias = (const float*)d_in[2];   // [16,192] f32
  float* out = (float*)d_out;                  // [4,4096,16,64] f32

  const size_t offW = 33554432;                       // Xb: 16M bf16
  const size_t offQ = offW + 6291456;                 // Wt: 3M bf16
  const size_t need_f32 = offQ + (size_t)16384*3072*4;
  const size_t need_b16 = offQ + (size_t)16384*3072*2;

  if (ws_size >= need_b16){
    u16* Xb = (u16*)d_ws;
    u16* Wt = (u16*)((char*)d_ws + offW);
    k_conv_x <<<2048, 256, 0, stream>>>(x, Xb, 16777216/4);
    k_conv_wt<<<dim3(96,32), 256, 0, stream>>>(wk, Wt);
    if (ws_size >= need_f32){
      float* Q = (float*)((char*)d_ws + offQ);
      k_gemm<float><<<3072, 256, 0, stream>>>(Xb, Wt, bias, Q);
      k_attn<float><<<4096, 256, 0, stream>>>(Q, out);
    } else {
      u16* Q = (u16*)((char*)d_ws + offQ);
      k_gemm<u16><<<3072, 256, 0, stream>>>(Xb, Wt, bias, Q);
      k_attn<u16><<<4096, 256, 0, stream>>>(Q, out);
    }
  } else {
    k_fallback<<<16384, 256, 0, stream>>>(x, wk, bias, out);
  }
}